// Round 1
// baseline (526.457 us; speedup 1.0000x reference)
//
#include <hip/hip_runtime.h>
#include <hip/hip_bf16.h>

// ---------------------------------------------------------------------------
// HoRA linear: out = x @ (base_w + (150*ifft2(sparse_spectrum)) @ A)^T + b
// M=8192, N=4096, K=4096.  bf16 MFMA GEMM with f32 accumulate.
// ---------------------------------------------------------------------------

#define OUTF 4096
#define INF  4096
#define RNK  16
#define NFREQ 10000
#define MDIM 8192

typedef __attribute__((ext_vector_type(8))) short bf16x8;
typedef __attribute__((ext_vector_type(4))) float f32x4;

__device__ __forceinline__ unsigned int bf16pack2(float a, float b) {
    unsigned int ua = __builtin_bit_cast(unsigned int, a);
    unsigned int ub = __builtin_bit_cast(unsigned int, b);
    ua = (ua + 0x7fffu + ((ua >> 16) & 1u)) >> 16;          // RNE
    ub = (ub + 0x7fffu + ((ub >> 16) & 1u)) & 0xffff0000u;  // RNE, keep high
    return ua | ub;
}

__device__ __forceinline__ void async_copy16(const void* g, void* l) {
    __builtin_amdgcn_global_load_lds(
        (__attribute__((address_space(1))) void*)(g),
        (__attribute__((address_space(3))) void*)(l),
        16, 0, 0);
}

// ---------------------------------------------------------------------------
// Kernel 1: B[o][r] = (150/16384) * sum_{nnz in chunk} val * cos(2*pi*phase)
// phase = (j*m)/1024 + (k*r)/16, chunk p = o/1024, m = o%1024.
// Sparse direct evaluation; ~2500 nnz per chunk.
// grid: 256 blocks x 256 thr; block b handles outputs [b*256, b*256+256),
// all inside chunk p = b/64.
// ---------------------------------------------------------------------------
__global__ __launch_bounds__(256) void build_B_kernel(
        const float* __restrict__ spectrum, const int* __restrict__ idx,
        float* __restrict__ Bout) {
    __shared__ int   s_jk[6144];
    __shared__ float s_v[6144];
    __shared__ int   s_cnt;
    const int tid = threadIdx.x;
    if (tid == 0) s_cnt = 0;
    __syncthreads();
    const int p = blockIdx.x >> 6;   // chunk 0..3
    for (int i = tid; i < NFREQ; i += 256) {
        int id = idx[i];
        if ((id >> 14) == p) {
            int pos = atomicAdd(&s_cnt, 1);
            if (pos < 6144) {
                s_jk[pos] = id & 16383;      // (j<<4)|k within chunk
                s_v[pos]  = spectrum[i];
            }
        }
    }
    __syncthreads();
    const int cnt = (s_cnt < 6144) ? s_cnt : 6144;
    const int gid = blockIdx.x * 256 + tid;   // 0..65535
    const int o = gid >> 4;
    const int r = gid & 15;
    const int m = o & 1023;
    const float c = 6.283185307179586f / 16384.f;
    float acc = 0.f;
    for (int t = 0; t < cnt; ++t) {
        int jk = s_jk[t];
        int j = jk >> 4, k = jk & 15;
        int ph = (((j * m) & 1023) << 4) + (((k * r) & 15) << 10);
        ph &= 16383;
        acc += s_v[t] * __cosf((float)ph * c);
    }
    Bout[gid] = acc * (150.f / 16384.f);
}

// ---------------------------------------------------------------------------
// Kernel 2: W_bf16[n][k] = bf16(base_w[n][k] + sum_r Bs[n][r] * A[r][k])
// 8 rows per block; A columns cached in registers across the 8 rows.
// grid: 512 blocks x 256 thr.
// ---------------------------------------------------------------------------
__global__ __launch_bounds__(256) void build_w_kernel(
        const float* __restrict__ bw, const float* __restrict__ A,
        const float* __restrict__ Bs, unsigned short* __restrict__ W) {
    const int n0 = blockIdx.x * 8;
    __shared__ float sB[8][16];
    if (threadIdx.x < 128)
        ((float*)sB)[threadIdx.x] = Bs[n0 * 16 + threadIdx.x];
    __syncthreads();
    const float4* A4 = (const float4*)A;
    const float4* bw4 = (const float4*)bw;
    uint2* W2 = (uint2*)W;
#pragma unroll 1
    for (int q = 0; q < 4; ++q) {
        const int c4 = threadIdx.x + q * 256;  // float4 column index [0,1024)
        float4 a[16];
#pragma unroll
        for (int r = 0; r < 16; ++r) a[r] = A4[r * 1024 + c4];
#pragma unroll 1
        for (int nn = 0; nn < 8; ++nn) {
            const int n = n0 + nn;
            float4 wv = bw4[n * 1024 + c4];
#pragma unroll
            for (int r = 0; r < 16; ++r) {
                float s = sB[nn][r];
                wv.x += s * a[r].x; wv.y += s * a[r].y;
                wv.z += s * a[r].z; wv.w += s * a[r].w;
            }
            W2[n * 1024 + c4] = make_uint2(bf16pack2(wv.x, wv.y),
                                           bf16pack2(wv.z, wv.w));
        }
    }
}

// ---------------------------------------------------------------------------
// Kernel 3: x (f32) -> bf16
// ---------------------------------------------------------------------------
__global__ __launch_bounds__(256) void cvt_x_kernel(
        const float4* __restrict__ x, uint2* __restrict__ xb, int n4) {
    for (int i = blockIdx.x * blockDim.x + threadIdx.x; i < n4;
         i += gridDim.x * blockDim.x) {
        float4 v = x[i];
        xb[i] = make_uint2(bf16pack2(v.x, v.y), bf16pack2(v.z, v.w));
    }
}

// ---------------------------------------------------------------------------
// Kernel 4: C[m][n] = sum_k Xb[m][k]*Wb[n][k] + bias[n]
// m97-structure: 128x128 tile, BK=32, 4 waves, 4x4 16x16x32 frags/wave,
// global_load_lds width-16 staging, 2 barriers per K-step.
// grid: 2048 blocks (64 M-tiles x 32 N-tiles) x 256 thr.
// ---------------------------------------------------------------------------
__global__ __launch_bounds__(256) void gemm_bt_kernel(
        const unsigned short* __restrict__ Xb,
        const unsigned short* __restrict__ Wb,
        const float* __restrict__ bias, float* __restrict__ C) {
    __shared__ unsigned short sA[128 * 32];
    __shared__ unsigned short sB[128 * 32];

    const int tid  = threadIdx.x;
    const int lane = tid & 63;
    const int w    = tid >> 6;
    const int wr   = w >> 1;   // 0..1
    const int wc   = w & 1;    // 0..1

    // XCD-bijective swizzle: nwg=2048, divisible by 8.
    int bid = blockIdx.x;
    bid = (bid & 7) * 256 + (bid >> 3);
    const int tn = bid & 31;   // N tile
    const int tm = bid >> 5;   // M tile
    const int arow0 = tm * 128;
    const int brow0 = tn * 128;

    f32x4 acc[4][4] = {};

    const int byte0 = tid * 16;
    const int l15   = lane & 15;
    const int koff  = (lane >> 4) * 8;

    for (int kk = 0; kk < INF; kk += 32) {
        // ---- stage A,B tiles (8192 B each) via global_load_lds x16 ----
#pragma unroll
        for (int q = 0; q < 2; ++q) {
            int b   = q * 4096 + byte0;
            int row = b >> 6;          // 0..127
            int cb  = (b & 63) >> 1;   // bf16 col 0..31
            async_copy16(Xb + (arow0 + row) * INF + kk + cb, (char*)sA + b);
            async_copy16(Wb + (brow0 + row) * INF + kk + cb, (char*)sB + b);
        }
        __syncthreads();   // compiler drains vmcnt before barrier

        // ---- fragments + 16 MFMA ----
        bf16x8 af[4], bfr[4];
#pragma unroll
        for (int i = 0; i < 4; ++i) {
            af[i]  = *(const bf16x8*)&sA[(wr * 64 + i * 16 + l15) * 32 + koff];
            bfr[i] = *(const bf16x8*)&sB[(wc * 64 + i * 16 + l15) * 32 + koff];
        }
#pragma unroll
        for (int i = 0; i < 4; ++i)
#pragma unroll
            for (int j = 0; j < 4; ++j)
                acc[i][j] = __builtin_amdgcn_mfma_f32_16x16x32_bf16(
                    af[i], bfr[j], acc[i][j], 0, 0, 0);
        __syncthreads();   // all reads done before next stage overwrites
    }

    // ---- epilogue: C = acc + bias ----
#pragma unroll
    for (int j = 0; j < 4; ++j) {
        const int n = brow0 + wc * 64 + j * 16 + l15;
        const float bv = bias[n];
#pragma unroll
        for (int i = 0; i < 4; ++i) {
            const int mbase = arow0 + wr * 64 + i * 16 + (lane >> 4) * 4;
#pragma unroll
            for (int rg = 0; rg < 4; ++rg) {
                C[(mbase + rg) * OUTF + n] = acc[i][j][rg] + bv;
            }
        }
    }
}

// ---------------------------------------------------------------------------
extern "C" void kernel_launch(void* const* d_in, const int* in_sizes, int n_in,
                              void* d_out, int out_size, void* d_ws, size_t ws_size,
                              hipStream_t stream) {
    const float* x    = (const float*)d_in[0];   // [4,2048,4096]
    const float* bw   = (const float*)d_in[1];   // [4096,4096]
    const float* bb   = (const float*)d_in[2];   // [4096]
    const float* spec = (const float*)d_in[3];   // [10000]
    const float* ha   = (const float*)d_in[4];   // [16,4096]
    const int*   idx  = (const int*)d_in[5];     // [10000]
    float* out = (float*)d_out;

    char* ws = (char*)d_ws;
    float*          Bbuf = (float*)ws;                              // 256 KB
    unsigned short* Wb   = (unsigned short*)(ws + 262144);          // 32 MB
    unsigned short* Xb   = (unsigned short*)(ws + 262144 + 33554432); // 64 MB

    build_B_kernel<<<256, 256, 0, stream>>>(spec, idx, Bbuf);
    build_w_kernel<<<512, 256, 0, stream>>>(bw, ha, Bbuf, Wb);
    cvt_x_kernel<<<2048, 256, 0, stream>>>((const float4*)x, (uint2*)Xb,
                                           (MDIM * INF) / 4);
    gemm_bt_kernel<<<2048, 256, 0, stream>>>(Xb, Wb, bb, out);
}

// Round 2
// 404.126 us; speedup vs baseline: 1.3027x; 1.3027x over previous
//
#include <hip/hip_runtime.h>
#include <hip/hip_bf16.h>

// ---------------------------------------------------------------------------
// HoRA linear: out = x @ (base_w + (150*ifft2(sparse_spectrum)) @ A)^T + b
// M=8192, N=4096, K=4096.  bf16 MFMA GEMM with f32 accumulate.
// GEMM: 256x256 tile, BK=64, 8 waves, 4-phase/K-tile schedule with counted
// vmcnt, XOR-swizzled LDS (both-sides), raw s_barrier + setprio.
// ---------------------------------------------------------------------------

#define OUTF 4096
#define INF  4096
#define NFREQ 10000
#define MDIM 8192
#define KT   (INF / 64)

typedef __attribute__((ext_vector_type(8))) short bf16x8;
typedef __attribute__((ext_vector_type(4))) float f32x4;

__device__ __forceinline__ unsigned int bf16pack2(float a, float b) {
    unsigned int ua = __builtin_bit_cast(unsigned int, a);
    unsigned int ub = __builtin_bit_cast(unsigned int, b);
    ua = (ua + 0x7fffu + ((ua >> 16) & 1u)) >> 16;          // RNE
    ub = (ub + 0x7fffu + ((ub >> 16) & 1u)) & 0xffff0000u;  // RNE, keep high
    return ua | ub;
}

__device__ __forceinline__ void async_copy16(const void* g, void* l) {
    __builtin_amdgcn_global_load_lds(
        (__attribute__((address_space(1))) void*)(g),
        (__attribute__((address_space(3))) void*)(l),
        16, 0, 0);
}

// ---------------------------------------------------------------------------
// Kernel 1: B[o][r] = (150/16384) * sum_{nnz in chunk} val * cos(2*pi*phase)
// ---------------------------------------------------------------------------
__global__ __launch_bounds__(256) void build_B_kernel(
        const float* __restrict__ spectrum, const int* __restrict__ idx,
        float* __restrict__ Bout) {
    __shared__ int   s_jk[6144];
    __shared__ float s_v[6144];
    __shared__ int   s_cnt;
    const int tid = threadIdx.x;
    if (tid == 0) s_cnt = 0;
    __syncthreads();
    const int p = blockIdx.x >> 6;   // chunk 0..3
    for (int i = tid; i < NFREQ; i += 256) {
        int id = idx[i];
        if ((id >> 14) == p) {
            int pos = atomicAdd(&s_cnt, 1);
            if (pos < 6144) {
                s_jk[pos] = id & 16383;      // (j<<4)|k within chunk
                s_v[pos]  = spectrum[i];
            }
        }
    }
    __syncthreads();
    const int cnt = (s_cnt < 6144) ? s_cnt : 6144;
    const int gid = blockIdx.x * 256 + tid;   // 0..65535
    const int o = gid >> 4;
    const int r = gid & 15;
    const int m = o & 1023;
    const float c = 6.283185307179586f / 16384.f;
    float acc = 0.f;
    for (int t = 0; t < cnt; ++t) {
        int jk = s_jk[t];
        int j = jk >> 4, k = jk & 15;
        int ph = (((j * m) & 1023) << 4) + (((k * r) & 15) << 10);
        ph &= 16383;
        acc += s_v[t] * __cosf((float)ph * c);
    }
    Bout[gid] = acc * (150.f / 16384.f);
}

// ---------------------------------------------------------------------------
// Kernel 2: W_bf16[n][k] = bf16(base_w[n][k] + sum_r Bs[n][r] * A[r][k])
// ---------------------------------------------------------------------------
__global__ __launch_bounds__(256) void build_w_kernel(
        const float* __restrict__ bw, const float* __restrict__ A,
        const float* __restrict__ Bs, unsigned short* __restrict__ W) {
    const int n0 = blockIdx.x * 8;
    __shared__ float sB[8][16];
    if (threadIdx.x < 128)
        ((float*)sB)[threadIdx.x] = Bs[n0 * 16 + threadIdx.x];
    __syncthreads();
    const float4* A4 = (const float4*)A;
    const float4* bw4 = (const float4*)bw;
    uint2* W2 = (uint2*)W;
#pragma unroll 1
    for (int q = 0; q < 4; ++q) {
        const int c4 = threadIdx.x + q * 256;
        float4 a[16];
#pragma unroll
        for (int r = 0; r < 16; ++r) a[r] = A4[r * 1024 + c4];
#pragma unroll 1
        for (int nn = 0; nn < 8; ++nn) {
            const int n = n0 + nn;
            float4 wv = bw4[n * 1024 + c4];
#pragma unroll
            for (int r = 0; r < 16; ++r) {
                float s = sB[nn][r];
                wv.x += s * a[r].x; wv.y += s * a[r].y;
                wv.z += s * a[r].z; wv.w += s * a[r].w;
            }
            W2[n * 1024 + c4] = make_uint2(bf16pack2(wv.x, wv.y),
                                           bf16pack2(wv.z, wv.w));
        }
    }
}

// ---------------------------------------------------------------------------
// Kernel 3: x (f32) -> bf16
// ---------------------------------------------------------------------------
__global__ __launch_bounds__(256) void cvt_x_kernel(
        const float4* __restrict__ x, uint2* __restrict__ xb, int n4) {
    for (int i = blockIdx.x * blockDim.x + threadIdx.x; i < n4;
         i += gridDim.x * blockDim.x) {
        float4 v = x[i];
        xb[i] = make_uint2(bf16pack2(v.x, v.y), bf16pack2(v.z, v.w));
    }
}

// ---------------------------------------------------------------------------
// Kernel 4: 256x256-tile 8-wave deep-pipelined bf16 GEMM.
// C[m][n] = sum_k Xb[m][k]*Wb[n][k] + bias[n]
// LDS per buffer: A 256x64 (32KB, rows of 128B) + B 256x64 (32KB); 2 buffers.
// Swizzle: byte_in_row ^= ((row&7)<<4), applied on the global source of
// global_load_lds (linear LDS dest) AND on the ds_read address.
// ---------------------------------------------------------------------------
__global__ __launch_bounds__(512, 2) void gemm256_kernel(
        const unsigned short* __restrict__ Xb,
        const unsigned short* __restrict__ Wb,
        const float* __restrict__ bias, float* __restrict__ C) {
    __shared__ __align__(1024) char lds[131072];

    const int tid  = threadIdx.x;
    const int lane = tid & 63;
    const int wid  = tid >> 6;
    const int wm   = wid >> 2;   // 0..1
    const int wn   = wid & 3;    // 0..3

    // XCD-bijective swizzle: nwg=512, divisible by 8.
    int bid = blockIdx.x;
    bid = (bid & 7) * 64 + (bid >> 3);
    const int tm = bid >> 4;     // 0..31  M tile
    const int tn = bid & 15;     // 0..15  N tile
    const int arow0 = tm * 256;
    const int brow0 = tn * 256;

    // staging constants: thread covers rows srow and srow+64 of a half-tile,
    // 16B chunk (tid&7); source col pre-swizzled so LDS holds swizzled layout.
    const int srow  = tid >> 3;                                // 0..63
    const int scole = (((tid & 7) * 16) ^ ((srow & 7) << 4)) >> 1;
    const int sldsb = tid * 16;

    // fragment-read constants: row = base + (lane&15); swizzle uses lane&7.
    const int l15 = lane & 15;
    const int kx0 = ((lane >> 4) * 16) ^ ((lane & 7) << 4);
    const int kx1 = kx0 ^ 64;
    const int abase0 = (wm * 128 + l15) * 128;           // A region at DB+0
    const int bbase0 = 32768 + (wn * 64 + l15) * 128;    // B region at DB+32768

    f32x4 acc[8][4] = {};
    bf16x8 af[4][2], bfa[2][2], bfb[2][2];

#define STAGE_HALF(mat, grow0, t, ldsbase) do {                               \
        const unsigned short* _s =                                            \
            (mat) + ((grow0) + srow) * INF + (t) * 64 + scole;                \
        async_copy16(_s, lds + (ldsbase) + sldsb);                            \
        async_copy16(_s + 64 * INF, lds + (ldsbase) + 8192 + sldsb);          \
    } while (0)

#define LDA(DB, m, kh) (*(const bf16x8*)(lds + (DB) + abase0 + (m) * 2048 + ((kh) ? kx1 : kx0)))
#define LDB(DB, n, kh) (*(const bf16x8*)(lds + (DB) + bbase0 + (n) * 2048 + ((kh) ? kx1 : kx0)))

#define MFMA(a, b, c) __builtin_amdgcn_mfma_f32_16x16x32_bf16((a), (b), (c), 0, 0, 0)

#define PH_OPEN()  __builtin_amdgcn_s_barrier();                              \
                   asm volatile("s_waitcnt lgkmcnt(0)" ::: "memory");         \
                   __builtin_amdgcn_s_setprio(1)
#define PH_CLOSE() __builtin_amdgcn_s_setprio(0);                             \
                   __builtin_amdgcn_s_barrier();                              \
                   asm volatile("" ::: "memory")

#define ITER(CUR, OTH, t) do {                                                \
    /* ---- phase 1: Q(mh0,nh0); stage A1(t+1) -> OTH ---- */                 \
    _Pragma("unroll") for (int m = 0; m < 4; ++m) {                           \
        af[m][0] = LDA(CUR, m, 0); af[m][1] = LDA(CUR, m, 1); }               \
    _Pragma("unroll") for (int n = 0; n < 2; ++n) {                           \
        bfa[n][0] = LDB(CUR, n, 0); bfa[n][1] = LDB(CUR, n, 1); }             \
    if ((t) + 1 < KT) STAGE_HALF(Xb, arow0 + 128, (t) + 1, (OTH) + 16384);    \
    PH_OPEN();                                                                \
    _Pragma("unroll") for (int m = 0; m < 4; ++m)                             \
        _Pragma("unroll") for (int n = 0; n < 2; ++n) {                       \
            acc[m][n] = MFMA(af[m][0], bfa[n][0], acc[m][n]);                 \
            acc[m][n] = MFMA(af[m][1], bfa[n][1], acc[m][n]); }               \
    PH_CLOSE();                                                               \
    /* ---- phase 2: Q(mh0,nh1); stage B0(t+1) -> OTH ---- */                 \
    _Pragma("unroll") for (int n = 0; n < 2; ++n) {                           \
        bfb[n][0] = LDB(CUR, n + 2, 0); bfb[n][1] = LDB(CUR, n + 2, 1); }     \
    if ((t) + 1 < KT) STAGE_HALF(Wb, brow0, (t) + 1, (OTH) + 32768);          \
    PH_OPEN();                                                                \
    _Pragma("unroll") for (int m = 0; m < 4; ++m)                             \
        _Pragma("unroll") for (int n = 0; n < 2; ++n) {                       \
            acc[m][n + 2] = MFMA(af[m][0], bfb[n][0], acc[m][n + 2]);         \
            acc[m][n + 2] = MFMA(af[m][1], bfb[n][1], acc[m][n + 2]); }       \
    PH_CLOSE();                                                               \
    /* ---- phase 3: Q(mh1,nh0); stage B1(t+1) -> OTH ---- */                 \
    _Pragma("unroll") for (int m = 0; m < 4; ++m) {                           \
        af[m][0] = LDA(CUR, m + 4, 0); af[m][1] = LDA(CUR, m + 4, 1); }       \
    if ((t) + 1 < KT) STAGE_HALF(Wb, brow0 + 128, (t) + 1, (OTH) + 49152);    \
    PH_OPEN();                                                                \
    _Pragma("unroll") for (int m = 0; m < 4; ++m)                             \
        _Pragma("unroll") for (int n = 0; n < 2; ++n) {                       \
            acc[m + 4][n] = MFMA(af[m][0], bfa[n][0], acc[m + 4][n]);         \
            acc[m + 4][n] = MFMA(af[m][1], bfa[n][1], acc[m + 4][n]); }       \
    PH_CLOSE();                                                               \
    /* ---- phase 4: Q(mh1,nh1); stage A0(t+2) -> CUR; counted vmcnt ---- */  \
    if ((t) + 2 < KT) STAGE_HALF(Xb, arow0, (t) + 2, (CUR));                  \
    __builtin_amdgcn_s_barrier();                                             \
    asm volatile("s_waitcnt lgkmcnt(0)" ::: "memory");                        \
    __builtin_amdgcn_s_setprio(1);                                            \
    _Pragma("unroll") for (int m = 0; m < 4; ++m)                             \
        _Pragma("unroll") for (int n = 0; n < 2; ++n) {                       \
            acc[m + 4][n + 2] = MFMA(af[m][0], bfb[n][0], acc[m + 4][n + 2]); \
            acc[m + 4][n + 2] = MFMA(af[m][1], bfb[n][1], acc[m + 4][n + 2]); \
        }                                                                     \
    __builtin_amdgcn_s_setprio(0);                                            \
    if ((t) + 2 < KT) { asm volatile("s_waitcnt vmcnt(2)" ::: "memory"); }    \
    else              { asm volatile("s_waitcnt vmcnt(0)" ::: "memory"); }    \
    __builtin_amdgcn_s_barrier();                                             \
    asm volatile("" ::: "memory");                                            \
} while (0)

    // ---- prologue: tile0 fully + tile1 A0; keep 2 loads in flight ----
    STAGE_HALF(Xb, arow0,       0, 0);
    STAGE_HALF(Xb, arow0 + 128, 0, 16384);
    STAGE_HALF(Wb, brow0,       0, 32768);
    STAGE_HALF(Wb, brow0 + 128, 0, 49152);
    STAGE_HALF(Xb, arow0,       1, 65536);
    asm volatile("s_waitcnt vmcnt(2)" ::: "memory");
    __builtin_amdgcn_s_barrier();
    asm volatile("" ::: "memory");

    for (int t = 0; t < KT; t += 2) {
        ITER(0, 65536, t);
        ITER(65536, 0, t + 1);
    }

    // ---- epilogue: C = acc + bias ----
#pragma unroll
    for (int n = 0; n < 4; ++n) {
        const int gcol = brow0 + wn * 64 + n * 16 + l15;
        const float bv = bias[gcol];
#pragma unroll
        for (int m = 0; m < 8; ++m) {
            const int grow = arow0 + wm * 128 + m * 16 + (lane >> 4) * 4;
#pragma unroll
            for (int rg = 0; rg < 4; ++rg)
                C[(grow + rg) * OUTF + gcol] = acc[m][n][rg] + bv;
        }
    }
#undef STAGE_HALF
#undef LDA
#undef LDB
#undef MFMA
#undef PH_OPEN
#undef PH_CLOSE
#undef ITER
}

// ---------------------------------------------------------------------------
extern "C" void kernel_launch(void* const* d_in, const int* in_sizes, int n_in,
                              void* d_out, int out_size, void* d_ws, size_t ws_size,
                              hipStream_t stream) {
    const float* x    = (const float*)d_in[0];   // [4,2048,4096]
    const float* bw   = (const float*)d_in[1];   // [4096,4096]
    const float* bb   = (const float*)d_in[2];   // [4096]
    const float* spec = (const float*)d_in[3];   // [10000]
    const float* ha   = (const float*)d_in[4];   // [16,4096]
    const int*   idx  = (const int*)d_in[5];     // [10000]
    float* out = (float*)d_out;

    char* ws = (char*)d_ws;
    float*          Bbuf = (float*)ws;                                // 256 KB
    unsigned short* Wb   = (unsigned short*)(ws + 262144);            // 32 MB
    unsigned short* Xb   = (unsigned short*)(ws + 262144 + 33554432); // 64 MB

    build_B_kernel<<<256, 256, 0, stream>>>(spec, idx, Bbuf);
    build_w_kernel<<<512, 256, 0, stream>>>(bw, ha, Bbuf, Wb);
    cvt_x_kernel<<<2048, 256, 0, stream>>>((const float4*)x, (uint2*)Xb,
                                           (MDIM * INF) / 4);
    gemm256_kernel<<<512, 512, 0, stream>>>(Xb, Wb, bb, out);
}